// Round 10
// baseline (228.389 us; speedup 1.0000x reference)
//
#include <hip/hip_runtime.h>
#include <math.h>

// Problem constants: N=32768 nodes, E=262144 edges, HID=64, HEADS=4
#define HIDDEN 64
#define HEADS 4
#define HC 256   // HEADS * HIDDEN
#define CAP 32   // bucket capacity per dst node (Poisson(8): P(deg>32) ~ 1e-12)

typedef __attribute__((ext_vector_type(8))) short short8;   // 8 bf16 (4 VGPRs)
typedef __attribute__((ext_vector_type(4))) float f32x4;    // MFMA acc

__device__ __forceinline__ unsigned short f2bf(float f) {
    unsigned int u = __float_as_uint(f);
    u += 0x7fffu + ((u >> 16) & 1u);   // round-to-nearest-even
    return (unsigned short)(u >> 16);
}

__device__ __forceinline__ unsigned short f2h(float f) {
    _Float16 h = (_Float16)f;          // v_cvt_f16_f32, RTN
    return *(unsigned short*)&h;
}

__device__ __forceinline__ float h2f(unsigned int u) {
    unsigned short s = (unsigned short)u;
    _Float16 h = *(_Float16*)&s;
    return (float)h;
}

__device__ __forceinline__ float bflo(unsigned int u) { return __uint_as_float(u << 16); }
__device__ __forceinline__ float bfhi(unsigned int u) { return __uint_as_float(u & 0xffff0000u); }

// ---------------- fused prep + bucket (R6-proven structure, CAP=32) ---------
// [0,1024):     bucket: eb[slot] = {src:u16, a0:f16}{a1:f16, a2:f16}
// [1024,3072):  zb = bf16(h)
// [3072,3200):  wst1/wst2[c*256+k] = bf16(0.25 * W[(k&63)*256 + (k>>6)*64 + c])
// [3200,3204):  wsv[r*256 + h*64 + k] = W @ att_{s/d} (r = layer*2 + type)
// 3204:         wr (We @ att_edge reductions, both layers)
// Requires counts==0 on entry (hipMemsetAsync before launch).
__global__ __launch_bounds__(256) void k_fused(const int* __restrict__ dst,
                                               const int* __restrict__ src,
                                               const float* __restrict__ ea,
                                               const float* __restrict__ h,
                                               const float* __restrict__ W1f,
                                               const float* __restrict__ W2f,
                                               const float* __restrict__ We1,
                                               const float* __restrict__ ae1,
                                               const float* __restrict__ We2,
                                               const float* __restrict__ ae2,
                                               const float* __restrict__ ats1,
                                               const float* __restrict__ atd1,
                                               const float* __restrict__ ats2,
                                               const float* __restrict__ atd2,
                                               int* __restrict__ counts,
                                               uint2* __restrict__ eb,
                                               ushort* __restrict__ zb,
                                               ushort* __restrict__ wst1,
                                               ushort* __restrict__ wst2,
                                               float* __restrict__ wsv,
                                               float* __restrict__ wr, int E) {
    int t = threadIdx.x, b = blockIdx.x;
    if (b < 1024) {
        int e = b * 256 + t;
        if (e < E) {
            int d = dst[e];
            int c = atomicAdd(&counts[d], 1);
            if (c < CAP) {   // statistically impossible overflow; safety clamp
                size_t slot = (size_t)d * CAP + c;
                unsigned int lo = (unsigned int)(src[e] & 0xffff)
                                | ((unsigned int)f2h(ea[e * 3 + 0]) << 16);
                unsigned int hi = (unsigned int)f2h(ea[e * 3 + 1])
                                | ((unsigned int)f2h(ea[e * 3 + 2]) << 16);
                eb[slot] = make_uint2(lo, hi);
            }
        }
    } else if (b < 3072) {
        int i = (b - 1024) * 256 + t;
        float4 v = ((const float4*)h)[i];
        ushort4 o;
        o.x = f2bf(v.x); o.y = f2bf(v.y); o.z = f2bf(v.z); o.w = f2bf(v.w);
        ((ushort4*)zb)[i] = o;
    } else if (b < 3200) {
        int j = (b - 3072) * 256 + t;        // 0..32767
        const float* W = (j < 16384) ? W1f : W2f;
        ushort* wst = (j < 16384) ? wst1 : wst2;
        int i = j & 16383;
        int c = i >> 8, k = i & 255;
        wst[i] = f2bf(0.25f * W[(k & 63) * HC + (k >> 6) * 64 + c]);
    } else if (b < 3204) {
        int r = b - 3200;                    // layer*2 + type
        const float* W = (r >> 1) ? W2f : W1f;
        const float* at;
        if (r == 0) at = ats1; else if (r == 1) at = atd1;
        else if (r == 2) at = ats2; else at = atd2;
        int hh = t >> 6, k = t & 63;
        const float4* wrow = (const float4*)&W[k * HC + hh * 64];
        const float4* arow = (const float4*)&at[hh * 64];
        float v = 0.f;
#pragma unroll
        for (int c4 = 0; c4 < 16; ++c4) {
            float4 wv = wrow[c4], av = arow[c4];
            v += wv.x * av.x + wv.y * av.y + wv.z * av.z + wv.w * av.w;
        }
        wsv[r * 256 + hh * 64 + k] = v;
    } else {
        int wv = t >> 6, lane = t & 63;
#pragma unroll
        for (int it = 0; it < 6; ++it) {
            int comb = wv + it * 4;          // 0..23
            int layer = comb / 12;
            int dh = comb % 12;
            int d = dh >> 2, hh = dh & 3;
            const float* We = layer ? We2 : We1;
            const float* at = layer ? ae2 : ae1;
            float v = We[d * HC + hh * HIDDEN + lane] * at[hh * HIDDEN + lane];
            for (int o = 32; o > 0; o >>= 1) v += __shfl_down(v, o);
            if (lane == 0) wr[layer * 16 + d * HEADS + hh] = v;
        }
    }
}

// ---------------- layer-1 alpha: as/ad = z @ ws/wd (R6-proven) ----------------
__global__ __launch_bounds__(256) void k_alpha(const ushort* __restrict__ zb,
                                               const float* __restrict__ wsv,
                                               float* __restrict__ as_,
                                               float* __restrict__ ad_) {
    __shared__ float ls[512];
    int t = threadIdx.x;
    ls[t] = wsv[t];
    ls[t + 256] = wsv[t + 256];
    __syncthreads();
    int n = blockIdx.x * 256 + t;
    const ushort* zr = zb + (size_t)n * HIDDEN;
    float as[4] = {0.f, 0.f, 0.f, 0.f};
    float ad[4] = {0.f, 0.f, 0.f, 0.f};
#pragma unroll
    for (int ks = 0; ks < 8; ++ks) {
        uint4 v = *(const uint4*)(zr + ks * 8);
        unsigned int uu[4] = {v.x, v.y, v.z, v.w};
#pragma unroll
        for (int p = 0; p < 4; ++p) {
            float f0 = bflo(uu[p]), f1 = bfhi(uu[p]);
            int k = ks * 8 + p * 2;
#pragma unroll
            for (int hh = 0; hh < 4; ++hh) {
                as[hh] += f0 * ls[hh * 64 + k] + f1 * ls[hh * 64 + k + 1];
                ad[hh] += f0 * ls[256 + hh * 64 + k] + f1 * ls[256 + hh * 64 + k + 1];
            }
        }
    }
    *(float4*)&as_[n * 4] = make_float4(as[0], as[1], as[2], as[3]);
    *(float4*)&ad_[n * 4] = make_float4(ad[0], ad[1], ad[2], ad[3]);
}

// ---------------- fused aggregate + out-GEMM (R6-proven, 8 blocks/CU) -------
// Block = 256 thr / 4 waves, owns 16 nodes (4 per wave).
// __launch_bounds__(256, 8): VGPR measured 64 at (256,4) = exactly the
// 8-waves/SIMD threshold -> request 8 blocks/CU for 2x latency hiding.
// Phase A: 4 independent eb record loads.  Phase B: 4 independent as_ gathers
// + exp.  Phase C: per-node gather/accumulate with reused acc[4][4].
// Then wave 0 runs the [16,256]@[256,64] MFMA out-GEMM + bias + LN + SiLU.
// Layer 1: writes bf16 z2 + fused as2/ad2. Layer 2: f32 d_out.
__global__ __launch_bounds__(256, 8) void k_aggout(
        const ushort* __restrict__ zb, const uint2* __restrict__ eb,
        const int* __restrict__ counts,
        const float* __restrict__ as_, const float* __restrict__ ad_,
        const float* __restrict__ wrl,
        const ushort* __restrict__ wst, const float* __restrict__ bias,
        const float* __restrict__ lng, const float* __restrict__ lnb,
        const float* __restrict__ wsv2,
        float* __restrict__ as2, float* __restrict__ ad2,
        float* __restrict__ outf, ushort* __restrict__ outb, int N) {
    __shared__ ushort sagg[16][264];   // 16 nodes x 256 ch bf16, +8 pad
    int lane = threadIdx.x & 63;
    int wave = threadIdx.x >> 6;
    int h = lane >> 4, sub = lane & 15;
    int nbase = blockIdx.x * 16;

    float w0 = wrl[h], w1 = wrl[4 + h], w2 = wrl[8 + h];

    int degs[4]; float ad4s[4]; int bases[4];
#pragma unroll
    for (int i = 0; i < 4; ++i) {
        int n = nbase + wave * 4 + i;
        int d = counts[n];
        degs[i] = (d > CAP) ? CAP : d;
        ad4s[i] = ad_[(size_t)n * 4 + h];
        bases[i] = n * CAP;
    }

    // phase A: batched chunk-0 record loads (4 independent)
    uint2 rec[4];
#pragma unroll
    for (int i = 0; i < 4; ++i) rec[i] = eb[bases[i] + sub];

    // phase B: batched as_ gathers + exp (4 independent chains)
    int s_sub[4]; float aq[4];
#pragma unroll
    for (int i = 0; i < 4; ++i)
        s_sub[i] = (sub < degs[i]) ? (int)(rec[i].x & 0xffffu) : 0;
#pragma unroll
    for (int i = 0; i < 4; ++i) aq[i] = as_[(size_t)s_sub[i] * 4 + h];
    float wgt[4];
#pragma unroll
    for (int i = 0; i < 4; ++i) {
        float wv = 0.f;
        if (sub < degs[i]) {
            float lg = aq[i] + ad4s[i]
                     + h2f(rec[i].x >> 16) * w0
                     + h2f(rec[i].y) * w1
                     + h2f(rec[i].y >> 16) * w2;
            lg = (lg >= 0.f) ? lg : 0.2f * lg;
            wv = __expf(lg);
        }
        wgt[i] = wv;
    }

    // phase C: per-node gather + reduce + LDS write (acc reused; no spill)
#pragma unroll 1
    for (int i = 0; i < 4; ++i) {
        int nl = wave * 4 + i;
        int deg = degs[i];
        float ssum = wgt[i];
        float acc[4][4];
#pragma unroll
        for (int aa = 0; aa < 4; ++aa)
#pragma unroll
            for (int j = 0; j < 4; ++j) acc[aa][j] = 0.f;

        int m0 = (deg > 16) ? 16 : deg;
        for (int j4 = 0; j4 < m0; j4 += 4) {
            int eidx = j4 + h;
            int s_g = __shfl(s_sub[i], eidx);
            uint2 zv = *(const uint2*)&zb[(size_t)s_g * HIDDEN + sub * 4];
            float z0 = bflo(zv.x), z1 = bfhi(zv.x);
            float z2v = bflo(zv.y), z3 = bfhi(zv.y);
#pragma unroll
            for (int hh = 0; hh < 4; ++hh) {
                float wh = __shfl(wgt[i], hh * 16 + eidx);
                acc[hh][0] += wh * z0;
                acc[hh][1] += wh * z1;
                acc[hh][2] += wh * z2v;
                acc[hh][3] += wh * z3;
            }
        }

        // tail chunk (deg > 16; CAP=32 so exactly one extra chunk max)
        for (int cs = 16; cs < deg; cs += 16) {
            int idx = cs + sub;
            int st = 0; float wt = 0.f;
            if (idx < deg) {
                uint2 rt = eb[bases[i] + idx];
                st = (int)(rt.x & 0xffffu);
                float lg = as_[(size_t)st * 4 + h] + ad4s[i]
                         + h2f(rt.x >> 16) * w0 + h2f(rt.y) * w1
                         + h2f(rt.y >> 16) * w2;
                lg = (lg >= 0.f) ? lg : 0.2f * lg;
                wt = __expf(lg);
            }
            ssum += wt;
            int jb = deg - cs; if (jb > 16) jb = 16;
            for (int j4 = 0; j4 < jb; j4 += 4) {
                int eidx = j4 + h;
                int s_g = __shfl(st, eidx);
                uint2 zv = *(const uint2*)&zb[(size_t)s_g * HIDDEN + sub * 4];
                float z0 = bflo(zv.x), z1 = bfhi(zv.x);
                float z2v = bflo(zv.y), z3 = bfhi(zv.y);
#pragma unroll
                for (int hh = 0; hh < 4; ++hh) {
                    float wh = __shfl(wt, hh * 16 + eidx);
                    acc[hh][0] += wh * z0;
                    acc[hh][1] += wh * z1;
                    acc[hh][2] += wh * z2v;
                    acc[hh][3] += wh * z3;
                }
            }
        }

        // softmax denom per head (reduce over bits 0..3 of lane)
#pragma unroll
        for (int o = 1; o < 16; o <<= 1) ssum += __shfl_xor(ssum, o);
        float winv = 1.f / (ssum + 1e-16f);
        // reduce acc over edge-slot groups (bits 4,5)
#pragma unroll
        for (int aa = 0; aa < 4; ++aa)
#pragma unroll
            for (int j = 0; j < 4; ++j) {
                acc[aa][j] += __shfl_xor(acc[aa][j], 16);
                acc[aa][j] += __shfl_xor(acc[aa][j], 32);
            }
        float sel[4];
#pragma unroll
        for (int j = 0; j < 4; ++j)
            sel[j] = (h == 0) ? acc[0][j] : (h == 1) ? acc[1][j]
                   : (h == 2) ? acc[2][j] : acc[3][j];
        uint2 pk;
        pk.x = (unsigned)f2bf(sel[0] * winv) | ((unsigned)f2bf(sel[1] * winv) << 16);
        pk.y = (unsigned)f2bf(sel[2] * winv) | ((unsigned)f2bf(sel[3] * winv) << 16);
        *(uint2*)&sagg[nl][h * 64 + sub * 4] = pk;
    }
    __syncthreads();

    if (wave == 0) {
        int q = lane & 15, quad = lane >> 4;
        short8 av[8];
#pragma unroll
        for (int ks = 0; ks < 8; ++ks)
            av[ks] = *(const short8*)&sagg[q][quad * 8 + ks * 32];

        f32x4 acc[4];
#pragma unroll
        for (int nt = 0; nt < 4; ++nt) {
            const ushort* brow = wst + (size_t)(nt * 16 + q) * HC + quad * 8;
            f32x4 c4 = {0.f, 0.f, 0.f, 0.f};
#pragma unroll
            for (int ks = 0; ks < 8; ++ks) {
                short8 bfr = *(const short8*)(brow + ks * 32);
                c4 = __builtin_amdgcn_mfma_f32_16x16x32_bf16(av[ks], bfr, c4, 0, 0, 0);
            }
            acc[nt] = c4;
        }

        // epilogue: bias (0.25 head-mean folded into wst) + LN + SiLU
        float u[4][4], s1[4] = {0.f, 0.f, 0.f, 0.f};
#pragma unroll
        for (int nt = 0; nt < 4; ++nt) {
            float bv = bias[nt * 16 + q];
#pragma unroll
            for (int r = 0; r < 4; ++r) { u[nt][r] = acc[nt][r] + bv; s1[r] += u[nt][r]; }
        }
#pragma unroll
        for (int o = 1; o < 16; o <<= 1)
#pragma unroll
            for (int r = 0; r < 4; ++r) s1[r] += __shfl_xor(s1[r], o);
        float mu[4], s2[4] = {0.f, 0.f, 0.f, 0.f};
#pragma unroll
        for (int r = 0; r < 4; ++r) mu[r] = s1[r] * (1.f / 64.f);
#pragma unroll
        for (int nt = 0; nt < 4; ++nt)
#pragma unroll
            for (int r = 0; r < 4; ++r) { float d = u[nt][r] - mu[r]; s2[r] += d * d; }
#pragma unroll
        for (int o = 1; o < 16; o <<= 1)
#pragma unroll
            for (int r = 0; r < 4; ++r) s2[r] += __shfl_xor(s2[r], o);
        float rstd[4];
#pragma unroll
        for (int r = 0; r < 4; ++r) rstd[r] = rsqrtf(s2[r] * (1.f / 64.f) + 1e-5f);

        float rv[4][4];
#pragma unroll
        for (int nt = 0; nt < 4; ++nt) {
            float gv = lng[nt * 16 + q], bb = lnb[nt * 16 + q];
#pragma unroll
            for (int r = 0; r < 4; ++r) {
                float y = (u[nt][r] - mu[r]) * rstd[r] * gv + bb;
                rv[nt][r] = y / (1.f + __expf(-y));
            }
        }

        if (outb) {
#pragma unroll
            for (int nt = 0; nt < 4; ++nt)
#pragma unroll
                for (int r = 0; r < 4; ++r)
                    outb[(size_t)(nbase + quad * 4 + r) * HIDDEN + nt * 16 + q] = f2bf(rv[nt][r]);
            // fused next-layer alpha: as2/ad2 = z2 @ ws2/wd2
            float vs[4][4] = {{0.f}}, vd[4][4] = {{0.f}};
#pragma unroll
            for (int hh = 0; hh < 4; ++hh)
#pragma unroll
                for (int nt = 0; nt < 4; ++nt) {
                    float wsc = wsv2[hh * 64 + nt * 16 + q];
                    float wdc = wsv2[256 + hh * 64 + nt * 16 + q];
#pragma unroll
                    for (int r = 0; r < 4; ++r) {
                        vs[r][hh] += rv[nt][r] * wsc;
                        vd[r][hh] += rv[nt][r] * wdc;
                    }
                }
#pragma unroll
            for (int o = 1; o < 16; o <<= 1)
#pragma unroll
                for (int r = 0; r < 4; ++r)
#pragma unroll
                    for (int hh = 0; hh < 4; ++hh) {
                        vs[r][hh] += __shfl_xor(vs[r][hh], o);
                        vd[r][hh] += __shfl_xor(vd[r][hh], o);
                    }
            if (q < 4) {
#pragma unroll
                for (int r = 0; r < 4; ++r) {
                    float sv = (q == 0) ? vs[r][0] : (q == 1) ? vs[r][1]
                             : (q == 2) ? vs[r][2] : vs[r][3];
                    float dv = (q == 0) ? vd[r][0] : (q == 1) ? vd[r][1]
                             : (q == 2) ? vd[r][2] : vd[r][3];
                    int n = nbase + quad * 4 + r;
                    as2[(size_t)n * 4 + q] = sv;
                    ad2[(size_t)n * 4 + q] = dv;
                }
            }
        } else {
#pragma unroll
            for (int nt = 0; nt < 4; ++nt)
#pragma unroll
                for (int r = 0; r < 4; ++r)
                    outf[(size_t)(nbase + quad * 4 + r) * HIDDEN + nt * 16 + q] = rv[nt][r];
        }
    }
}

// ---------------- launch ----------------

extern "C" void kernel_launch(void* const* d_in, const int* in_sizes, int n_in,
                              void* d_out, int out_size, void* d_ws, size_t ws_size,
                              hipStream_t stream) {
    const float* h   = (const float*)d_in[1];
    const int*   ei  = (const int*)d_in[2];
    const float* ea  = (const float*)d_in[3];
    const float* W1  = (const float*)d_in[4];
    const float* We1 = (const float*)d_in[5];
    const float* as1 = (const float*)d_in[6];
    const float* ad1 = (const float*)d_in[7];
    const float* ae1 = (const float*)d_in[8];
    const float* b1  = (const float*)d_in[9];
    const float* lg1 = (const float*)d_in[10];
    const float* lb1 = (const float*)d_in[11];
    const float* W2  = (const float*)d_in[12];
    const float* We2 = (const float*)d_in[13];
    const float* as2 = (const float*)d_in[14];
    const float* ad2 = (const float*)d_in[15];
    const float* ae2 = (const float*)d_in[16];
    const float* b2  = (const float*)d_in[17];
    const float* lg2 = (const float*)d_in[18];
    const float* lb2 = (const float*)d_in[19];

    const int N = in_sizes[1] / HIDDEN;   // 32768
    const int E = in_sizes[2] / 2;        // 262144
    const int* srcp = ei;
    const int* dstp = ei + E;

    // workspace layout (all regions fully written before read)
    char* w = (char*)d_ws;
    ushort* zb    = (ushort*)w; w += (size_t)N * HIDDEN * 2;    // 4 MB  (z1)
    ushort* zb2   = (ushort*)w; w += (size_t)N * HIDDEN * 2;    // 4 MB  (z2)
    float* as_    = (float*)w;  w += (size_t)N * HEADS * 4;
    float* adv    = (float*)w;  w += (size_t)N * HEADS * 4;
    float* as2_   = (float*)w;  w += (size_t)N * HEADS * 4;
    float* ad2_   = (float*)w;  w += (size_t)N * HEADS * 4;
    ushort* wst1  = (ushort*)w; w += 16384 * 2;
    ushort* wst2  = (ushort*)w; w += 16384 * 2;
    float* wsv    = (float*)w;  w += 1024 * 4;                  // [r=0..3][256]
    float* wr     = (float*)w;  w += 128;
    int* counts   = (int*)w;    w += (size_t)N * 4;
    uint2* eb     = (uint2*)w;  w += (size_t)N * CAP * 8;       // 8 MB packed records

    // zero counts, then fused prep (bucket || zb || weights)
    hipMemsetAsync(counts, 0, (size_t)N * 4, stream);
    k_fused<<<3205, 256, 0, stream>>>(dstp, srcp, ea, h, W1, W2,
                                      We1, ae1, We2, ae2,
                                      as1, ad1, as2, ad2,
                                      counts, eb, zb, wst1, wst2, wsv, wr, E);

    k_alpha<<<N / 256, 256, 0, stream>>>(zb, wsv, as_, adv);

    // layer 1: aggregate z1 + out-GEMM -> z2 (bf16) + as2/ad2
    k_aggout<<<N / 16, 256, 0, stream>>>(zb, eb, counts, as_, adv, wr,
                                         wst1, b1, lg1, lb1, wsv + 512,
                                         as2_, ad2_, nullptr, zb2, N);
    // layer 2: aggregate z2 + out-GEMM -> d_out (f32)
    k_aggout<<<N / 16, 256, 0, stream>>>(zb2, eb, counts, as2_, ad2_, wr + 16,
                                         wst2, b2, lg2, lb2, nullptr,
                                         nullptr, nullptr, (float*)d_out, nullptr, N);
}

// Round 11
// 188.945 us; speedup vs baseline: 1.2088x; 1.2088x over previous
//
#include <hip/hip_runtime.h>
#include <math.h>

// Problem constants: N=32768 nodes, E=262144 edges, HID=64, HEADS=4
#define HIDDEN 64
#define HEADS 4
#define HC 256   // HEADS * HIDDEN
#define CAP 32   // bucket capacity per dst node (Poisson(8): P(deg>32) ~ 1e-12)

typedef __attribute__((ext_vector_type(8))) short short8;   // 8 bf16 (4 VGPRs)
typedef __attribute__((ext_vector_type(4))) float f32x4;    // MFMA acc

__device__ __forceinline__ unsigned short f2bf(float f) {
    unsigned int u = __float_as_uint(f);
    u += 0x7fffu + ((u >> 16) & 1u);   // round-to-nearest-even
    return (unsigned short)(u >> 16);
}

__device__ __forceinline__ unsigned short f2h(float f) {
    _Float16 h = (_Float16)f;          // v_cvt_f16_f32, RTN
    return *(unsigned short*)&h;
}

__device__ __forceinline__ float h2f(unsigned int u) {
    unsigned short s = (unsigned short)u;
    _Float16 h = *(_Float16*)&s;
    return (float)h;
}

__device__ __forceinline__ float bflo(unsigned int u) { return __uint_as_float(u << 16); }
__device__ __forceinline__ float bfhi(unsigned int u) { return __uint_as_float(u & 0xffff0000u); }

// ---------------- fused prep + bucket (bucket MLP-batched 4 edges/thread) ---
// [0,256):      bucket: 4 edges/thread, int4/float4 coalesced loads, 4
//               independent atomic+scatter chains in flight (latency MLP)
// [256,2304):   zb = bf16(h)
// [2304,2432):  wst1/wst2[c*256+k] = bf16(0.25 * W[(k&63)*256 + (k>>6)*64 + c])
// [2432,2436):  wsv[r*256 + h*64 + k] = W @ att_{s/d} (r = layer*2 + type)
// 2436:         wr (We @ att_edge reductions, both layers)
// Requires counts==0 on entry (hipMemsetAsync before launch).
__global__ __launch_bounds__(256) void k_fused(const int* __restrict__ dst,
                                               const int* __restrict__ src,
                                               const float* __restrict__ ea,
                                               const float* __restrict__ h,
                                               const float* __restrict__ W1f,
                                               const float* __restrict__ W2f,
                                               const float* __restrict__ We1,
                                               const float* __restrict__ ae1,
                                               const float* __restrict__ We2,
                                               const float* __restrict__ ae2,
                                               const float* __restrict__ ats1,
                                               const float* __restrict__ atd1,
                                               const float* __restrict__ ats2,
                                               const float* __restrict__ atd2,
                                               int* __restrict__ counts,
                                               uint2* __restrict__ eb,
                                               ushort* __restrict__ zb,
                                               ushort* __restrict__ wst1,
                                               ushort* __restrict__ wst2,
                                               float* __restrict__ wsv,
                                               float* __restrict__ wr, int E) {
    int t = threadIdx.x, b = blockIdx.x;
    if (b < 256) {
        int q = b * 256 + t;                 // quad index; 4 edges per thread
        int4 d4 = ((const int4*)dst)[q];
        int4 s4 = ((const int4*)src)[q];
        float4 e0 = ((const float4*)ea)[q * 3 + 0];
        float4 e1 = ((const float4*)ea)[q * 3 + 1];
        float4 e2 = ((const float4*)ea)[q * 3 + 2];
        int dd[4] = {d4.x, d4.y, d4.z, d4.w};
        int ss[4] = {s4.x, s4.y, s4.z, s4.w};
        float a0[4] = {e0.x, e0.w, e1.z, e2.y};
        float a1[4] = {e0.y, e1.x, e1.w, e2.z};
        float a2[4] = {e0.z, e1.y, e2.x, e2.w};
        int cc[4];
#pragma unroll
        for (int i = 0; i < 4; ++i) cc[i] = atomicAdd(&counts[dd[i]], 1);
#pragma unroll
        for (int i = 0; i < 4; ++i) {
            if (cc[i] < CAP) {   // statistically impossible overflow; safety clamp
                size_t slot = (size_t)dd[i] * CAP + cc[i];
                unsigned int lo = (unsigned int)(ss[i] & 0xffff)
                                | ((unsigned int)f2h(a0[i]) << 16);
                unsigned int hi = (unsigned int)f2h(a1[i])
                                | ((unsigned int)f2h(a2[i]) << 16);
                eb[slot] = make_uint2(lo, hi);
            }
        }
    } else if (b < 2304) {
        int i = (b - 256) * 256 + t;
        float4 v = ((const float4*)h)[i];
        ushort4 o;
        o.x = f2bf(v.x); o.y = f2bf(v.y); o.z = f2bf(v.z); o.w = f2bf(v.w);
        ((ushort4*)zb)[i] = o;
    } else if (b < 2432) {
        int j = (b - 2304) * 256 + t;        // 0..32767
        const float* W = (j < 16384) ? W1f : W2f;
        ushort* wst = (j < 16384) ? wst1 : wst2;
        int i = j & 16383;
        int c = i >> 8, k = i & 255;
        wst[i] = f2bf(0.25f * W[(k & 63) * HC + (k >> 6) * 64 + c]);
    } else if (b < 2436) {
        int r = b - 2432;                    // layer*2 + type
        const float* W = (r >> 1) ? W2f : W1f;
        const float* at;
        if (r == 0) at = ats1; else if (r == 1) at = atd1;
        else if (r == 2) at = ats2; else at = atd2;
        int hh = t >> 6, k = t & 63;
        const float4* wrow = (const float4*)&W[k * HC + hh * 64];
        const float4* arow = (const float4*)&at[hh * 64];
        float v = 0.f;
#pragma unroll
        for (int c4 = 0; c4 < 16; ++c4) {
            float4 wv = wrow[c4], av = arow[c4];
            v += wv.x * av.x + wv.y * av.y + wv.z * av.z + wv.w * av.w;
        }
        wsv[r * 256 + hh * 64 + k] = v;
    } else {
        int wv = t >> 6, lane = t & 63;
#pragma unroll
        for (int it = 0; it < 6; ++it) {
            int comb = wv + it * 4;          // 0..23
            int layer = comb / 12;
            int dh = comb % 12;
            int d = dh >> 2, hh = dh & 3;
            const float* We = layer ? We2 : We1;
            const float* at = layer ? ae2 : ae1;
            float v = We[d * HC + hh * HIDDEN + lane] * at[hh * HIDDEN + lane];
            for (int o = 32; o > 0; o >>= 1) v += __shfl_down(v, o);
            if (lane == 0) wr[layer * 16 + d * HEADS + hh] = v;
        }
    }
}

// ---------------- layer-1 alpha: as/ad = z @ ws/wd (R6-proven) ----------------
__global__ __launch_bounds__(256) void k_alpha(const ushort* __restrict__ zb,
                                               const float* __restrict__ wsv,
                                               float* __restrict__ as_,
                                               float* __restrict__ ad_) {
    __shared__ float ls[512];
    int t = threadIdx.x;
    ls[t] = wsv[t];
    ls[t + 256] = wsv[t + 256];
    __syncthreads();
    int n = blockIdx.x * 256 + t;
    const ushort* zr = zb + (size_t)n * HIDDEN;
    float as[4] = {0.f, 0.f, 0.f, 0.f};
    float ad[4] = {0.f, 0.f, 0.f, 0.f};
#pragma unroll
    for (int ks = 0; ks < 8; ++ks) {
        uint4 v = *(const uint4*)(zr + ks * 8);
        unsigned int uu[4] = {v.x, v.y, v.z, v.w};
#pragma unroll
        for (int p = 0; p < 4; ++p) {
            float f0 = bflo(uu[p]), f1 = bfhi(uu[p]);
            int k = ks * 8 + p * 2;
#pragma unroll
            for (int hh = 0; hh < 4; ++hh) {
                as[hh] += f0 * ls[hh * 64 + k] + f1 * ls[hh * 64 + k + 1];
                ad[hh] += f0 * ls[256 + hh * 64 + k] + f1 * ls[256 + hh * 64 + k + 1];
            }
        }
    }
    *(float4*)&as_[n * 4] = make_float4(as[0], as[1], as[2], as[3]);
    *(float4*)&ad_[n * 4] = make_float4(ad[0], ad[1], ad[2], ad[3]);
}

// ---------------- fused aggregate + out-GEMM (R6-proven, (256,4)) -----------
// Block = 256 thr / 4 waves, owns 16 nodes (4 per wave).
// (256,4): natural VGPR=64 already permits 8 blocks/CU residency; requesting
// 8 as a floor forces VGPR=32 + ~80 MB scratch spill (R10 measured) — never.
// Phase A: 4 independent eb record loads.  Phase B: 4 independent as_ gathers
// + exp.  Phase C: per-node gather/accumulate with reused acc[4][4].
// Then wave 0 runs the [16,256]@[256,64] MFMA out-GEMM + bias + LN + SiLU.
// Layer 1: writes bf16 z2 + fused as2/ad2. Layer 2: f32 d_out.
__global__ __launch_bounds__(256, 4) void k_aggout(
        const ushort* __restrict__ zb, const uint2* __restrict__ eb,
        const int* __restrict__ counts,
        const float* __restrict__ as_, const float* __restrict__ ad_,
        const float* __restrict__ wrl,
        const ushort* __restrict__ wst, const float* __restrict__ bias,
        const float* __restrict__ lng, const float* __restrict__ lnb,
        const float* __restrict__ wsv2,
        float* __restrict__ as2, float* __restrict__ ad2,
        float* __restrict__ outf, ushort* __restrict__ outb, int N) {
    __shared__ ushort sagg[16][264];   // 16 nodes x 256 ch bf16, +8 pad
    int lane = threadIdx.x & 63;
    int wave = threadIdx.x >> 6;
    int h = lane >> 4, sub = lane & 15;
    int nbase = blockIdx.x * 16;

    float w0 = wrl[h], w1 = wrl[4 + h], w2 = wrl[8 + h];

    int degs[4]; float ad4s[4]; int bases[4];
#pragma unroll
    for (int i = 0; i < 4; ++i) {
        int n = nbase + wave * 4 + i;
        int d = counts[n];
        degs[i] = (d > CAP) ? CAP : d;
        ad4s[i] = ad_[(size_t)n * 4 + h];
        bases[i] = n * CAP;
    }

    // phase A: batched chunk-0 record loads (4 independent)
    uint2 rec[4];
#pragma unroll
    for (int i = 0; i < 4; ++i) rec[i] = eb[bases[i] + sub];

    // phase B: batched as_ gathers + exp (4 independent chains)
    int s_sub[4]; float aq[4];
#pragma unroll
    for (int i = 0; i < 4; ++i)
        s_sub[i] = (sub < degs[i]) ? (int)(rec[i].x & 0xffffu) : 0;
#pragma unroll
    for (int i = 0; i < 4; ++i) aq[i] = as_[(size_t)s_sub[i] * 4 + h];
    float wgt[4];
#pragma unroll
    for (int i = 0; i < 4; ++i) {
        float wv = 0.f;
        if (sub < degs[i]) {
            float lg = aq[i] + ad4s[i]
                     + h2f(rec[i].x >> 16) * w0
                     + h2f(rec[i].y) * w1
                     + h2f(rec[i].y >> 16) * w2;
            lg = (lg >= 0.f) ? lg : 0.2f * lg;
            wv = __expf(lg);
        }
        wgt[i] = wv;
    }

    // phase C: per-node gather + reduce + LDS write (acc reused; no spill)
#pragma unroll 1
    for (int i = 0; i < 4; ++i) {
        int nl = wave * 4 + i;
        int deg = degs[i];
        float ssum = wgt[i];
        float acc[4][4];
#pragma unroll
        for (int aa = 0; aa < 4; ++aa)
#pragma unroll
            for (int j = 0; j < 4; ++j) acc[aa][j] = 0.f;

        int m0 = (deg > 16) ? 16 : deg;
        for (int j4 = 0; j4 < m0; j4 += 4) {
            int eidx = j4 + h;
            int s_g = __shfl(s_sub[i], eidx);
            uint2 zv = *(const uint2*)&zb[(size_t)s_g * HIDDEN + sub * 4];
            float z0 = bflo(zv.x), z1 = bfhi(zv.x);
            float z2v = bflo(zv.y), z3 = bfhi(zv.y);
#pragma unroll
            for (int hh = 0; hh < 4; ++hh) {
                float wh = __shfl(wgt[i], hh * 16 + eidx);
                acc[hh][0] += wh * z0;
                acc[hh][1] += wh * z1;
                acc[hh][2] += wh * z2v;
                acc[hh][3] += wh * z3;
            }
        }

        // tail chunk (deg > 16; CAP=32 so exactly one extra chunk max)
        for (int cs = 16; cs < deg; cs += 16) {
            int idx = cs + sub;
            int st = 0; float wt = 0.f;
            if (idx < deg) {
                uint2 rt = eb[bases[i] + idx];
                st = (int)(rt.x & 0xffffu);
                float lg = as_[(size_t)st * 4 + h] + ad4s[i]
                         + h2f(rt.x >> 16) * w0 + h2f(rt.y) * w1
                         + h2f(rt.y >> 16) * w2;
                lg = (lg >= 0.f) ? lg : 0.2f * lg;
                wt = __expf(lg);
            }
            ssum += wt;
            int jb = deg - cs; if (jb > 16) jb = 16;
            for (int j4 = 0; j4 < jb; j4 += 4) {
                int eidx = j4 + h;
                int s_g = __shfl(st, eidx);
                uint2 zv = *(const uint2*)&zb[(size_t)s_g * HIDDEN + sub * 4];
                float z0 = bflo(zv.x), z1 = bfhi(zv.x);
                float z2v = bflo(zv.y), z3 = bfhi(zv.y);
#pragma unroll
                for (int hh = 0; hh < 4; ++hh) {
                    float wh = __shfl(wt, hh * 16 + eidx);
                    acc[hh][0] += wh * z0;
                    acc[hh][1] += wh * z1;
                    acc[hh][2] += wh * z2v;
                    acc[hh][3] += wh * z3;
                }
            }
        }

        // softmax denom per head (reduce over bits 0..3 of lane)
#pragma unroll
        for (int o = 1; o < 16; o <<= 1) ssum += __shfl_xor(ssum, o);
        float winv = 1.f / (ssum + 1e-16f);
        // reduce acc over edge-slot groups (bits 4,5)
#pragma unroll
        for (int aa = 0; aa < 4; ++aa)
#pragma unroll
            for (int j = 0; j < 4; ++j) {
                acc[aa][j] += __shfl_xor(acc[aa][j], 16);
                acc[aa][j] += __shfl_xor(acc[aa][j], 32);
            }
        float sel[4];
#pragma unroll
        for (int j = 0; j < 4; ++j)
            sel[j] = (h == 0) ? acc[0][j] : (h == 1) ? acc[1][j]
                   : (h == 2) ? acc[2][j] : acc[3][j];
        uint2 pk;
        pk.x = (unsigned)f2bf(sel[0] * winv) | ((unsigned)f2bf(sel[1] * winv) << 16);
        pk.y = (unsigned)f2bf(sel[2] * winv) | ((unsigned)f2bf(sel[3] * winv) << 16);
        *(uint2*)&sagg[nl][h * 64 + sub * 4] = pk;
    }
    __syncthreads();

    if (wave == 0) {
        int q = lane & 15, quad = lane >> 4;
        short8 av[8];
#pragma unroll
        for (int ks = 0; ks < 8; ++ks)
            av[ks] = *(const short8*)&sagg[q][quad * 8 + ks * 32];

        f32x4 acc[4];
#pragma unroll
        for (int nt = 0; nt < 4; ++nt) {
            const ushort* brow = wst + (size_t)(nt * 16 + q) * HC + quad * 8;
            f32x4 c4 = {0.f, 0.f, 0.f, 0.f};
#pragma unroll
            for (int ks = 0; ks < 8; ++ks) {
                short8 bfr = *(const short8*)(brow + ks * 32);
                c4 = __builtin_amdgcn_mfma_f32_16x16x32_bf16(av[ks], bfr, c4, 0, 0, 0);
            }
            acc[nt] = c4;
        }

        // epilogue: bias (0.25 head-mean folded into wst) + LN + SiLU
        float u[4][4], s1[4] = {0.f, 0.f, 0.f, 0.f};
#pragma unroll
        for (int nt = 0; nt < 4; ++nt) {
            float bv = bias[nt * 16 + q];
#pragma unroll
            for (int r = 0; r < 4; ++r) { u[nt][r] = acc[nt][r] + bv; s1[r] += u[nt][r]; }
        }
#pragma unroll
        for (int o = 1; o < 16; o <<= 1)
#pragma unroll
            for (int r = 0; r < 4; ++r) s1[r] += __shfl_xor(s1[r], o);
        float mu[4], s2[4] = {0.f, 0.f, 0.f, 0.f};
#pragma unroll
        for (int r = 0; r < 4; ++r) mu[r] = s1[r] * (1.f / 64.f);
#pragma unroll
        for (int nt = 0; nt < 4; ++nt)
#pragma unroll
            for (int r = 0; r < 4; ++r) { float d = u[nt][r] - mu[r]; s2[r] += d * d; }
#pragma unroll
        for (int o = 1; o < 16; o <<= 1)
#pragma unroll
            for (int r = 0; r < 4; ++r) s2[r] += __shfl_xor(s2[r], o);
        float rstd[4];
#pragma unroll
        for (int r = 0; r < 4; ++r) rstd[r] = rsqrtf(s2[r] * (1.f / 64.f) + 1e-5f);

        float rv[4][4];
#pragma unroll
        for (int nt = 0; nt < 4; ++nt) {
            float gv = lng[nt * 16 + q], bb = lnb[nt * 16 + q];
#pragma unroll
            for (int r = 0; r < 4; ++r) {
                float y = (u[nt][r] - mu[r]) * rstd[r] * gv + bb;
                rv[nt][r] = y / (1.f + __expf(-y));
            }
        }

        if (outb) {
#pragma unroll
            for (int nt = 0; nt < 4; ++nt)
#pragma unroll
                for (int r = 0; r < 4; ++r)
                    outb[(size_t)(nbase + quad * 4 + r) * HIDDEN + nt * 16 + q] = f2bf(rv[nt][r]);
            // fused next-layer alpha: as2/ad2 = z2 @ ws2/wd2
            float vs[4][4] = {{0.f}}, vd[4][4] = {{0.f}};
#pragma unroll
            for (int hh = 0; hh < 4; ++hh)
#pragma unroll
                for (int nt = 0; nt < 4; ++nt) {
                    float wsc = wsv2[hh * 64 + nt * 16 + q];
                    float wdc = wsv2[256 + hh * 64 + nt * 16 + q];
#pragma unroll
                    for (int r = 0; r < 4; ++r) {
                        vs[r][hh] += rv[nt][r] * wsc;
                        vd[r][hh] += rv[nt][r] * wdc;
                    }
                }
#pragma unroll
            for (int o = 1; o < 16; o <<= 1)
#pragma unroll
                for (int r = 0; r < 4; ++r)
#pragma unroll
                    for (int hh = 0; hh < 4; ++hh) {
                        vs[r][hh] += __shfl_xor(vs[r][hh], o);
                        vd[r][hh] += __shfl_xor(vd[r][hh], o);
                    }
            if (q < 4) {
#pragma unroll
                for (int r = 0; r < 4; ++r) {
                    float sv = (q == 0) ? vs[r][0] : (q == 1) ? vs[r][1]
                             : (q == 2) ? vs[r][2] : vs[r][3];
                    float dv = (q == 0) ? vd[r][0] : (q == 1) ? vd[r][1]
                             : (q == 2) ? vd[r][2] : vd[r][3];
                    int n = nbase + quad * 4 + r;
                    as2[(size_t)n * 4 + q] = sv;
                    ad2[(size_t)n * 4 + q] = dv;
                }
            }
        } else {
#pragma unroll
            for (int nt = 0; nt < 4; ++nt)
#pragma unroll
                for (int r = 0; r < 4; ++r)
                    outf[(size_t)(nbase + quad * 4 + r) * HIDDEN + nt * 16 + q] = rv[nt][r];
        }
    }
}

// ---------------- launch ----------------

extern "C" void kernel_launch(void* const* d_in, const int* in_sizes, int n_in,
                              void* d_out, int out_size, void* d_ws, size_t ws_size,
                              hipStream_t stream) {
    const float* h   = (const float*)d_in[1];
    const int*   ei  = (const int*)d_in[2];
    const float* ea  = (const float*)d_in[3];
    const float* W1  = (const float*)d_in[4];
    const float* We1 = (const float*)d_in[5];
    const float* as1 = (const float*)d_in[6];
    const float* ad1 = (const float*)d_in[7];
    const float* ae1 = (const float*)d_in[8];
    const float* b1  = (const float*)d_in[9];
    const float* lg1 = (const float*)d_in[10];
    const float* lb1 = (const float*)d_in[11];
    const float* W2  = (const float*)d_in[12];
    const float* We2 = (const float*)d_in[13];
    const float* as2 = (const float*)d_in[14];
    const float* ad2 = (const float*)d_in[15];
    const float* ae2 = (const float*)d_in[16];
    const float* b2  = (const float*)d_in[17];
    const float* lg2 = (const float*)d_in[18];
    const float* lb2 = (const float*)d_in[19];

    const int N = in_sizes[1] / HIDDEN;   // 32768
    const int E = in_sizes[2] / 2;        // 262144
    const int* srcp = ei;
    const int* dstp = ei + E;

    // workspace layout (all regions fully written before read)
    char* w = (char*)d_ws;
    ushort* zb    = (ushort*)w; w += (size_t)N * HIDDEN * 2;    // 4 MB  (z1)
    ushort* zb2   = (ushort*)w; w += (size_t)N * HIDDEN * 2;    // 4 MB  (z2)
    float* as_    = (float*)w;  w += (size_t)N * HEADS * 4;
    float* adv    = (float*)w;  w += (size_t)N * HEADS * 4;
    float* as2_   = (float*)w;  w += (size_t)N * HEADS * 4;
    float* ad2_   = (float*)w;  w += (size_t)N * HEADS * 4;
    ushort* wst1  = (ushort*)w; w += 16384 * 2;
    ushort* wst2  = (ushort*)w; w += 16384 * 2;
    float* wsv    = (float*)w;  w += 1024 * 4;                  // [r=0..3][256]
    float* wr     = (float*)w;  w += 128;
    int* counts   = (int*)w;    w += (size_t)N * 4;
    uint2* eb     = (uint2*)w;  w += (size_t)N * CAP * 8;       // 8 MB packed records

    // zero counts, then fused prep (bucket || zb || weights)
    hipMemsetAsync(counts, 0, (size_t)N * 4, stream);
    k_fused<<<2437, 256, 0, stream>>>(dstp, srcp, ea, h, W1, W2,
                                      We1, ae1, We2, ae2,
                                      as1, ad1, as2, ad2,
                                      counts, eb, zb, wst1, wst2, wsv, wr, E);

    k_alpha<<<N / 256, 256, 0, stream>>>(zb, wsv, as_, adv);

    // layer 1: aggregate z1 + out-GEMM -> z2 (bf16) + as2/ad2
    k_aggout<<<N / 16, 256, 0, stream>>>(zb, eb, counts, as_, adv, wr,
                                         wst1, b1, lg1, lb1, wsv + 512,
                                         as2_, ad2_, nullptr, zb2, N);
    // layer 2: aggregate z2 + out-GEMM -> d_out (f32)
    k_aggout<<<N / 16, 256, 0, stream>>>(zb2, eb, counts, as2_, ad2_, wr + 16,
                                         wst2, b2, lg2, lb2, nullptr,
                                         nullptr, nullptr, (float*)d_out, nullptr, N);
}